// Round 12
// baseline (442.632 us; speedup 1.0000x reference)
//
#include <hip/hip_runtime.h>

#define NGRAPH 100000
#define NPG 9
#define EPG 36
#define WPB 8                 // waves per block
#define BLOCK (WPB * 64)
#define GRID 1024             // grid-stride, ~12 graphs/wave

// Compiler-only ordering fence. Same-wave DS ops are processed in order by
// the LDS pipe, and the compiler inserts register-dependency lgkmcnt waits
// itself — we only need to stop compiler reordering, not drain the queue.
#define CBAR() asm volatile("" ::: "memory")

typedef float v2f __attribute__((ext_vector_type(2)));
__device__ __forceinline__ v2f pkfma(v2f a, v2f b, v2f c) {
  return __builtin_elementwise_fma(a, b, c);
}

// DPP wave64 sum: row_shr 1/2/4/8 (row-inclusive-scan) + row_bcast15/31.
// dpp_ctrl must be an ICE -> template parameter.
// bound_ctrl=true -> invalid source lanes contribute 0. Result in lane 63.
template <int CTRL>
__device__ __forceinline__ float dppadd(float v) {
  int t = __builtin_amdgcn_mov_dpp(__float_as_int(v), CTRL, 0xf, 0xf, true);
  return v + __int_as_float(t);
}
__device__ __forceinline__ float wavesum63(float v) {
  v = dppadd<0x111>(v);   // row_shr:1
  v = dppadd<0x112>(v);   // row_shr:2
  v = dppadd<0x114>(v);   // row_shr:4
  v = dppadd<0x118>(v);   // row_shr:8  -> lanes 15/31/47/63 hold row sums
  v = dppadd<0x142>(v);   // row_bcast:15
  v = dppadd<0x143>(v);   // row_bcast:31 -> lane 63 holds wave total
  return v;
}

struct __align__(16) WS {
  float xg[144];   // x tile [9][16]
  float A[108];    // adjacency [9][12], cols 9..11 stay zero
  float h1[288];   // relu(conv1) [9][32]
  float eb[192];   // e0[64] | e8[64] | ctx[64] broadcast buffer
};

__global__ __launch_bounds__(BLOCK, 2) void gqn(
    const float* __restrict__ x,
    const int* __restrict__ ei,
    const float* __restrict__ W1, const float* __restrict__ b1,
    const float* __restrict__ W2, const float* __restrict__ b2,
    const float* __restrict__ fc1w, const float* __restrict__ fc1b,
    const float* __restrict__ fc2w, const float* __restrict__ fc2b,
    float* __restrict__ out)
{
  // fc1 transposed [j=64][k=128], 16B-chunk XOR-swizzled (chunk ^= j&7):
  // per-lane ds_read_b128 row reads spread across all 8 bank-quads.
  __shared__ float fc1T[64 * 128];
  __shared__ WS ws[WPB];

  const int tid  = threadIdx.x;
  const int lane = tid & 63;
  const int wib  = tid >> 6;
  const int f1   = lane & 31;

  // ---- one-time: stage fc1_w into swizzled LDS (coalesced global read) ----
  for (int idx = tid; idx < 128 * 64; idx += BLOCK) {
    int k = idx >> 6, j = idx & 63;
    int pc = (k >> 2) ^ (j & 7);               // physical 16B chunk
    fc1T[j * 128 + (pc << 2) + (k & 3)] = fc1w[idx];
  }
  __syncthreads();

  // ---- per-lane register weight caches (scalar: keep pressure <=128) ----
  float w1c[16], w2c[32];
#pragma unroll
  for (int k = 0; k < 16; ++k) w1c[k] = W1[k * 32 + f1];
  const float b1c = b1[f1];
#pragma unroll
  for (int k = 0; k < 32; ++k) w2c[k] = W2[k * 64 + lane];
  const float b2c   = b2[lane];
  const float fc1bc = fc1b[lane];
  const float fc2wc = fc2w[lane];
  const float fc2bs = fc2b[0];

  WS* S = &ws[wib];
  const int* srcp = ei;
  const int* dstp = ei + NGRAPH * EPG;
  const int gw = blockIdx.x * WPB + wib;
  const int nw = GRID * WPB;

  // ---- prologue prefetch for first graph ----
  float4 xv = make_float4(0.f, 0.f, 0.f, 0.f);
  int es = -1, ed = -1;
  if (gw < NGRAPH && lane < 36) {
    xv = ((const float4*)(x + (size_t)gw * 144))[lane];
    es = srcp[gw * EPG + lane] - gw * NPG;
    ed = dstp[gw * EPG + lane] - gw * NPG;
  }

  for (int g = gw; g < NGRAPH; g += nw) {
    CBAR();  // order vs prev-iter LDS reads (HW DS pipe is in-order per wave)

    // ---- stage x tile (prefetched regs), zero A ----
    if (lane < 36) ((float4*)S->xg)[lane] = xv;
    if (lane < 27) ((float4*)S->A)[lane] = make_float4(0.f, 0.f, 0.f, 0.f);

    // ---- issue next graph's prefetch (hides HBM latency under compute) ----
    float4 xv2 = make_float4(0.f, 0.f, 0.f, 0.f);
    int es2 = -1, ed2 = -1;
    const int g2 = g + nw;
    if (g2 < NGRAPH && lane < 36) {
      xv2 = ((const float4*)(x + (size_t)g2 * 144))[lane];
      es2 = srcp[g2 * EPG + lane] - g2 * NPG;
      ed2 = dstp[g2 * EPG + lane] - g2 * NPG;
    }

    // ---- degree via ballot (no LDS traffic): deg[n] = 1 + #dst==n ----
    int cnt = 0;
#pragma unroll
    for (int n = 0; n < 9; ++n) {
      unsigned long long bm = __ballot(ed == n);
      if (lane == n) cnt = (int)__popcll(bm);
    }
    float dvl = 0.f;
    if (lane < 9) dvl = rsqrtf(1.f + (float)cnt);   // dinv in lane n

    // norm for this lane's edge: dinv[es]*dinv[ed] via bpermute
    float dv_s = __int_as_float(__builtin_amdgcn_ds_bpermute(es << 2, __float_as_int(dvl)));
    float dv_d = __int_as_float(__builtin_amdgcn_ds_bpermute(ed << 2, __float_as_int(dvl)));
    float nrm = dv_s * dv_d;

    // ---- build A (LDS atomics; DS in-order after the zeroing writes) ----
    if (lane < 36) atomicAdd(&S->A[ed * 12 + es], nrm);
    if (lane < 9)  atomicAdd(&S->A[lane * 12 + lane], dvl * dvl);
    CBAR();  // keep A reads below the atomics

    // ---- GCN1 matmul: h1t[n] = x[n,:] . W1[:,f1] ----
    float h1t[9];
#pragma unroll
    for (int n = 0; n < 9; ++n) {
      const float4* xr = (const float4*)(S->xg + n * 16);
      float4 x0 = xr[0], x1 = xr[1], x2 = xr[2], x3 = xr[3];
      float acc = 0.f;
      acc = fmaf(x0.x, w1c[0],  acc);
      acc = fmaf(x0.y, w1c[1],  acc);
      acc = fmaf(x0.z, w1c[2],  acc);
      acc = fmaf(x0.w, w1c[3],  acc);
      acc = fmaf(x1.x, w1c[4],  acc);
      acc = fmaf(x1.y, w1c[5],  acc);
      acc = fmaf(x1.z, w1c[6],  acc);
      acc = fmaf(x1.w, w1c[7],  acc);
      acc = fmaf(x2.x, w1c[8],  acc);
      acc = fmaf(x2.y, w1c[9],  acc);
      acc = fmaf(x2.z, w1c[10], acc);
      acc = fmaf(x2.w, w1c[11], acc);
      acc = fmaf(x3.x, w1c[12], acc);
      acc = fmaf(x3.y, w1c[13], acc);
      acc = fmaf(x3.z, w1c[14], acc);
      acc = fmaf(x3.w, w1c[15], acc);
      h1t[n] = acc;
    }

    // ---- GCN1 aggregate + bias + relu -> LDS h1[9][32] ----
    {
      v2f hp0 = (v2f){h1t[0], h1t[1]}, hp1 = (v2f){h1t[2], h1t[3]};
      v2f hp2 = (v2f){h1t[4], h1t[5]}, hp3 = (v2f){h1t[6], h1t[7]};
#pragma unroll
      for (int n = 0; n < 9; ++n) {
        const float4* Ar = (const float4*)(S->A + n * 12);
        float4 a0 = Ar[0], a1 = Ar[1];
        float  a8 = S->A[n * 12 + 8];
        v2f acc = (v2f){0.f, 0.f};
        acc = pkfma((v2f){a0.x, a0.y}, hp0, acc);
        acc = pkfma((v2f){a0.z, a0.w}, hp1, acc);
        acc = pkfma((v2f){a1.x, a1.y}, hp2, acc);
        acc = pkfma((v2f){a1.z, a1.w}, hp3, acc);
        float r = fmaf(a8, h1t[8], acc.x + acc.y + b1c);
        if (lane < 32) S->h1[n * 32 + f1] = fmaxf(r, 0.f);
      }
    }
    CBAR();  // h1 writes ordered before h1 reads (in-order DS)

    // ---- GCN2 matmul: h2t[n] = h1[n,:] . W2[:,lane] ----
    float h2t[9];
#pragma unroll
    for (int n = 0; n < 9; ++n) {
      const float4* hr = (const float4*)(S->h1 + n * 32);
      float acc = 0.f;
#pragma unroll
      for (int q = 0; q < 8; ++q) {
        float4 hv = hr[q];
        acc = fmaf(hv.x, w2c[4*q+0], acc);
        acc = fmaf(hv.y, w2c[4*q+1], acc);
        acc = fmaf(hv.z, w2c[4*q+2], acc);
        acc = fmaf(hv.w, w2c[4*q+3], acc);
      }
      h2t[n] = acc;
    }

    // ---- GCN2 aggregate + relu; pool ctx; station rows ----
    float e0 = 0.f, e8 = 0.f, ctx = 0.f;
    {
      v2f gp0 = (v2f){h2t[0], h2t[1]}, gp1 = (v2f){h2t[2], h2t[3]};
      v2f gp2 = (v2f){h2t[4], h2t[5]}, gp3 = (v2f){h2t[6], h2t[7]};
#pragma unroll
      for (int n = 0; n < 9; ++n) {
        const float4* Ar = (const float4*)(S->A + n * 12);
        float4 a0 = Ar[0], a1 = Ar[1];
        float  a8 = S->A[n * 12 + 8];
        v2f acc = (v2f){0.f, 0.f};
        acc = pkfma((v2f){a0.x, a0.y}, gp0, acc);
        acc = pkfma((v2f){a0.z, a0.w}, gp1, acc);
        acc = pkfma((v2f){a1.x, a1.y}, gp2, acc);
        acc = pkfma((v2f){a1.z, a1.w}, gp3, acc);
        float r = fmaxf(fmaf(a8, h2t[8], acc.x + acc.y + b2c), 0.f);
        ctx += r;
        if (n == 0) e0 = r;
        if (n == 8) e8 = r;
      }
    }
    ctx *= (1.f / 9.f);

    // ---- publish combined vector to LDS for uniform broadcast ----
    S->eb[lane]       = e0;
    S->eb[64 + lane]  = e8;
    S->eb[128 + lane] = ctx;
    CBAR();  // eb writes ordered before eb reads (in-order DS)

    // ---- heads: out[j=lane] = relu(comb . fc1[:,j] + b); swizzled b128 rows ----
    v2f a0p = (v2f){0.f, 0.f}, a8p = (v2f){0.f, 0.f}, acp = (v2f){0.f, 0.f};
    const float* Wbase = fc1T + lane * 128;
    const int    sw    = (lane & 7) << 2;         // chunk-XOR in float units
    const float4* E0   = (const float4*)(S->eb);
#pragma unroll 4
    for (int q = 0; q < 16; ++q) {      // chunks 0..15 : k = 0..63 (stations)
      float4 wv = *(const float4*)(Wbase + ((q << 2) ^ sw));
      float4 s0 = E0[q];
      float4 s8 = E0[16 + q];
      a0p = pkfma((v2f){wv.x, wv.y}, (v2f){s0.x, s0.y}, a0p);
      a0p = pkfma((v2f){wv.z, wv.w}, (v2f){s0.z, s0.w}, a0p);
      a8p = pkfma((v2f){wv.x, wv.y}, (v2f){s8.x, s8.y}, a8p);
      a8p = pkfma((v2f){wv.z, wv.w}, (v2f){s8.z, s8.w}, a8p);
    }
#pragma unroll 4
    for (int q = 16; q < 32; ++q) {     // chunks 16..31 : k = 64..127 (ctx)
      float4 wc = *(const float4*)(Wbase + ((q << 2) ^ sw));
      float4 sc = E0[16 + q];
      acp = pkfma((v2f){wc.x, wc.y}, (v2f){sc.x, sc.y}, acp);
      acp = pkfma((v2f){wc.z, wc.w}, (v2f){sc.z, sc.w}, acp);
    }
    float accC = acp.x + acp.y;
    float r0 = fmaxf(a0p.x + a0p.y + fc1bc + accC, 0.f);
    float r8 = fmaxf(a8p.x + a8p.y + fc1bc + accC, 0.f);

    // ---- fc2 + DPP wave reduce (VALU, no LDS) + store from lane 63 ----
    float p0 = wavesum63(r0 * fc2wc);
    float p8 = wavesum63(r8 * fc2wc);
    if (lane == 63) {
      ((float2*)out)[g] = make_float2(p0 + fc2bs, p8 + fc2bs);
    }

    // rotate prefetch
    xv = xv2; es = es2; ed = ed2;
  }
}

extern "C" void kernel_launch(void* const* d_in, const int* in_sizes, int n_in,
                              void* d_out, int out_size, void* d_ws, size_t ws_size,
                              hipStream_t stream) {
  const float* x    = (const float*)d_in[0];
  const int*   ei   = (const int*)d_in[1];
  // d_in[2] = batch (unused: graph id = node/9, counts always 9)
  const float* W1   = (const float*)d_in[3];
  const float* b1   = (const float*)d_in[4];
  const float* W2   = (const float*)d_in[5];
  const float* b2   = (const float*)d_in[6];
  const float* fc1w = (const float*)d_in[7];
  const float* fc1b = (const float*)d_in[8];
  const float* fc2w = (const float*)d_in[9];
  const float* fc2b = (const float*)d_in[10];
  float* out = (float*)d_out;

  hipLaunchKernelGGL(gqn, dim3(GRID), dim3(BLOCK), 0, stream,
                     x, ei, W1, b1, W2, b2, fc1w, fc1b, fc2w, fc2b, out);
}

// Round 14
// 391.818 us; speedup vs baseline: 1.1297x; 1.1297x over previous
//
#include <hip/hip_runtime.h>

#define NGRAPH 100000
#define NPG 9
#define EPG 36
#define WPB 8                 // waves per block
#define BLOCK (WPB * 64)
#define GRID 1024             // grid-stride, ~12 graphs/wave

// wave-level LDS fence (per-wave workspace; lanes lockstep)
#define WSYNC() asm volatile("s_waitcnt lgkmcnt(0)" ::: "memory")

// DPP wave64 sum: row_shr 1/2/4/8 (row-inclusive-scan) + row_bcast15/31.
// dpp_ctrl must be an ICE -> template parameter.
// bound_ctrl=true -> invalid source lanes contribute 0. Result in lane 63.
template <int CTRL>
__device__ __forceinline__ float dppadd(float v) {
  int t = __builtin_amdgcn_mov_dpp(__float_as_int(v), CTRL, 0xf, 0xf, true);
  return v + __int_as_float(t);
}
__device__ __forceinline__ float wavesum63(float v) {
  v = dppadd<0x111>(v);   // row_shr:1
  v = dppadd<0x112>(v);   // row_shr:2
  v = dppadd<0x114>(v);   // row_shr:4
  v = dppadd<0x118>(v);   // row_shr:8  -> lanes 15/31/47/63 hold row sums
  v = dppadd<0x142>(v);   // row_bcast:15
  v = dppadd<0x143>(v);   // row_bcast:31 -> lane 63 holds wave total
  return v;
}

struct __align__(16) WS {
  float xg[144];   // x tile [9][16]
  float A[108];    // adjacency [9][12], cols 9..11 stay zero
  float h1[288];   // relu(conv1) [9][32]
  float eb[192];   // e0[64] | e8[64] | ctx[64] broadcast buffer
};

__global__ __launch_bounds__(BLOCK, 2) void gqn(
    const float* __restrict__ x,
    const int* __restrict__ ei,
    const float* __restrict__ W1, const float* __restrict__ b1,
    const float* __restrict__ W2, const float* __restrict__ b2,
    const float* __restrict__ fc1w, const float* __restrict__ fc1b,
    const float* __restrict__ fc2w, const float* __restrict__ fc2b,
    float* __restrict__ out)
{
  // fc1 transposed [j=64][k=128], 16B-chunk XOR-swizzled (chunk ^= j&7):
  // per-lane ds_read_b128 row reads spread across all 8 bank-quads.
  __shared__ float fc1T[64 * 128];
  __shared__ WS ws[WPB];

  const int tid  = threadIdx.x;
  const int lane = tid & 63;
  const int wib  = tid >> 6;
  const int f1   = lane & 31;

  // ---- one-time: stage fc1_w into swizzled LDS (coalesced global read) ----
  for (int idx = tid; idx < 128 * 64; idx += BLOCK) {
    int k = idx >> 6, j = idx & 63;
    int pc = (k >> 2) ^ (j & 7);               // physical 16B chunk
    fc1T[j * 128 + (pc << 2) + (k & 3)] = fc1w[idx];
  }
  __syncthreads();

  // ---- per-lane register weight caches (scalar: keep pressure ~116) ----
  float w1c[16], w2c[32];
#pragma unroll
  for (int k = 0; k < 16; ++k) w1c[k] = W1[k * 32 + f1];
  const float b1c = b1[f1];
#pragma unroll
  for (int k = 0; k < 32; ++k) w2c[k] = W2[k * 64 + lane];
  const float b2c   = b2[lane];
  const float fc1bc = fc1b[lane];
  const float fc2wc = fc2w[lane];
  const float fc2bs = fc2b[0];

  WS* S = &ws[wib];
  const int* srcp = ei;
  const int* dstp = ei + NGRAPH * EPG;
  const int gw = blockIdx.x * WPB + wib;
  const int nw = GRID * WPB;

  // ---- prologue prefetch for first graph ----
  float4 xv = make_float4(0.f, 0.f, 0.f, 0.f);
  int es = -1, ed = -1;
  if (gw < NGRAPH && lane < 36) {
    xv = ((const float4*)(x + (size_t)gw * 144))[lane];
    es = srcp[gw * EPG + lane] - gw * NPG;
    ed = dstp[gw * EPG + lane] - gw * NPG;
  }

  for (int g = gw; g < NGRAPH; g += nw) {
    WSYNC();  // prev-iter LDS reads drained before overwriting

    // ---- stage x tile (prefetched regs), zero A ----
    if (lane < 36) ((float4*)S->xg)[lane] = xv;
    if (lane < 27) ((float4*)S->A)[lane] = make_float4(0.f, 0.f, 0.f, 0.f);

    // ---- issue next graph's prefetch (hides HBM latency under compute) ----
    float4 xv2 = make_float4(0.f, 0.f, 0.f, 0.f);
    int es2 = -1, ed2 = -1;
    const int g2 = g + nw;
    if (g2 < NGRAPH && lane < 36) {
      xv2 = ((const float4*)(x + (size_t)g2 * 144))[lane];
      es2 = srcp[g2 * EPG + lane] - g2 * NPG;
      ed2 = dstp[g2 * EPG + lane] - g2 * NPG;
    }

    // ---- degree via ballot (no LDS atomics): deg[n] = 1 + #dst==n ----
    int cnt = 0;
#pragma unroll
    for (int n = 0; n < 9; ++n) {
      unsigned long long bm = __ballot(ed == n);
      if (lane == n) cnt = (int)__popcll(bm);
    }
    float dvl = 0.f;
    if (lane < 9) dvl = rsqrtf(1.f + (float)cnt);   // dinv in lane n

    // norm for this lane's edge: dinv[es]*dinv[ed] via bpermute
    float dv_s = __int_as_float(__builtin_amdgcn_ds_bpermute(es << 2, __float_as_int(dvl)));
    float dv_d = __int_as_float(__builtin_amdgcn_ds_bpermute(ed << 2, __float_as_int(dvl)));
    float nrm = dv_s * dv_d;

    // ---- build A (LDS atomics; same-wave DS in-order after zeroing) ----
    if (lane < 36) atomicAdd(&S->A[ed * 12 + es], nrm);
    if (lane < 9)  atomicAdd(&S->A[lane * 12 + lane], dvl * dvl);

    // ---- GCN1 matmul: h1t[n] = x[n,:] . W1[:,f1] ----
    float h1t[9];
#pragma unroll
    for (int n = 0; n < 9; ++n) {
      const float4* xr = (const float4*)(S->xg + n * 16);
      float4 x0 = xr[0], x1 = xr[1], x2 = xr[2], x3 = xr[3];
      float acc = 0.f;
      acc = fmaf(x0.x, w1c[0],  acc);
      acc = fmaf(x0.y, w1c[1],  acc);
      acc = fmaf(x0.z, w1c[2],  acc);
      acc = fmaf(x0.w, w1c[3],  acc);
      acc = fmaf(x1.x, w1c[4],  acc);
      acc = fmaf(x1.y, w1c[5],  acc);
      acc = fmaf(x1.z, w1c[6],  acc);
      acc = fmaf(x1.w, w1c[7],  acc);
      acc = fmaf(x2.x, w1c[8],  acc);
      acc = fmaf(x2.y, w1c[9],  acc);
      acc = fmaf(x2.z, w1c[10], acc);
      acc = fmaf(x2.w, w1c[11], acc);
      acc = fmaf(x3.x, w1c[12], acc);
      acc = fmaf(x3.y, w1c[13], acc);
      acc = fmaf(x3.z, w1c[14], acc);
      acc = fmaf(x3.w, w1c[15], acc);
      h1t[n] = acc;
    }
    WSYNC();  // A atomics complete

    // ---- GCN1 aggregate + bias + relu -> LDS h1[9][32] ----
#pragma unroll
    for (int n = 0; n < 9; ++n) {
      const float4* Ar = (const float4*)(S->A + n * 12);
      float4 a0 = Ar[0], a1 = Ar[1];
      float  a8 = S->A[n * 12 + 8];
      float acc = b1c;
      acc = fmaf(a0.x, h1t[0], acc);
      acc = fmaf(a0.y, h1t[1], acc);
      acc = fmaf(a0.z, h1t[2], acc);
      acc = fmaf(a0.w, h1t[3], acc);
      acc = fmaf(a1.x, h1t[4], acc);
      acc = fmaf(a1.y, h1t[5], acc);
      acc = fmaf(a1.z, h1t[6], acc);
      acc = fmaf(a1.w, h1t[7], acc);
      acc = fmaf(a8,   h1t[8], acc);
      if (lane < 32) S->h1[n * 32 + f1] = fmaxf(acc, 0.f);
    }
    WSYNC();  // h1 visible

    // ---- GCN2 matmul: h2t[n] = h1[n,:] . W2[:,lane] ----
    float h2t[9];
#pragma unroll
    for (int n = 0; n < 9; ++n) {
      const float4* hr = (const float4*)(S->h1 + n * 32);
      float acc = 0.f;
#pragma unroll
      for (int q = 0; q < 8; ++q) {
        float4 hv = hr[q];
        acc = fmaf(hv.x, w2c[4*q+0], acc);
        acc = fmaf(hv.y, w2c[4*q+1], acc);
        acc = fmaf(hv.z, w2c[4*q+2], acc);
        acc = fmaf(hv.w, w2c[4*q+3], acc);
      }
      h2t[n] = acc;
    }

    // ---- GCN2 aggregate + relu; pool ctx; station rows ----
    float e0 = 0.f, e8 = 0.f, ctx = 0.f;
#pragma unroll
    for (int n = 0; n < 9; ++n) {
      const float4* Ar = (const float4*)(S->A + n * 12);
      float4 a0 = Ar[0], a1 = Ar[1];
      float  a8 = S->A[n * 12 + 8];
      float acc = b2c;
      acc = fmaf(a0.x, h2t[0], acc);
      acc = fmaf(a0.y, h2t[1], acc);
      acc = fmaf(a0.z, h2t[2], acc);
      acc = fmaf(a0.w, h2t[3], acc);
      acc = fmaf(a1.x, h2t[4], acc);
      acc = fmaf(a1.y, h2t[5], acc);
      acc = fmaf(a1.z, h2t[6], acc);
      acc = fmaf(a1.w, h2t[7], acc);
      acc = fmaf(a8,   h2t[8], acc);
      float r = fmaxf(acc, 0.f);
      ctx += r;
      if (n == 0) e0 = r;
      if (n == 8) e8 = r;
    }
    ctx *= (1.f / 9.f);

    // ---- publish combined vector to LDS for uniform broadcast ----
    S->eb[lane]       = e0;
    S->eb[64 + lane]  = e8;
    S->eb[128 + lane] = ctx;
    WSYNC();

    // ---- heads: out[j=lane] = relu(comb . fc1[:,j] + b); swizzled b128 rows ----
    float acc0 = fc1bc, acc8 = fc1bc, accC = 0.f;
    const float* Wbase = fc1T + lane * 128;
    const int    sw    = (lane & 7) << 2;         // chunk-XOR in float units
    const float4* E0   = (const float4*)(S->eb);
#pragma unroll 4
    for (int q = 0; q < 16; ++q) {      // chunks 0..15 : k = 0..63 (stations)
      float4 wv = *(const float4*)(Wbase + ((q << 2) ^ sw));
      float4 s0 = E0[q];
      float4 s8 = E0[16 + q];
      acc0 = fmaf(wv.x, s0.x, acc0);
      acc0 = fmaf(wv.y, s0.y, acc0);
      acc0 = fmaf(wv.z, s0.z, acc0);
      acc0 = fmaf(wv.w, s0.w, acc0);
      acc8 = fmaf(wv.x, s8.x, acc8);
      acc8 = fmaf(wv.y, s8.y, acc8);
      acc8 = fmaf(wv.z, s8.z, acc8);
      acc8 = fmaf(wv.w, s8.w, acc8);
    }
#pragma unroll 4
    for (int q = 16; q < 32; ++q) {     // chunks 16..31 : k = 64..127 (ctx)
      float4 wc = *(const float4*)(Wbase + ((q << 2) ^ sw));
      float4 sc = E0[16 + q];
      accC = fmaf(wc.x, sc.x, accC);
      accC = fmaf(wc.y, sc.y, accC);
      accC = fmaf(wc.z, sc.z, accC);
      accC = fmaf(wc.w, sc.w, accC);
    }
    float r0 = fmaxf(acc0 + accC, 0.f);
    float r8 = fmaxf(acc8 + accC, 0.f);

    // ---- fc2 + DPP wave reduce (VALU, no LDS) + store from lane 63 ----
    float p0 = wavesum63(r0 * fc2wc);
    float p8 = wavesum63(r8 * fc2wc);
    if (lane == 63) {
      ((float2*)out)[g] = make_float2(p0 + fc2bs, p8 + fc2bs);
    }

    // rotate prefetch
    xv = xv2; es = es2; ed = ed2;
  }
}

extern "C" void kernel_launch(void* const* d_in, const int* in_sizes, int n_in,
                              void* d_out, int out_size, void* d_ws, size_t ws_size,
                              hipStream_t stream) {
  const float* x    = (const float*)d_in[0];
  const int*   ei   = (const int*)d_in[1];
  // d_in[2] = batch (unused: graph id = node/9, counts always 9)
  const float* W1   = (const float*)d_in[3];
  const float* b1   = (const float*)d_in[4];
  const float* W2   = (const float*)d_in[5];
  const float* b2   = (const float*)d_in[6];
  const float* fc1w = (const float*)d_in[7];
  const float* fc1b = (const float*)d_in[8];
  const float* fc2w = (const float*)d_in[9];
  const float* fc2b = (const float*)d_in[10];
  float* out = (float*)d_out;

  hipLaunchKernelGGL(gqn, dim3(GRID), dim3(BLOCK), 0, stream,
                     x, ei, W1, b1, W2, b2, fc1w, fc1b, fc2w, fc2b, out);
}